// Round 18
// baseline (47.487 us; speedup 1.0000x reference)
//
#include <hip/hip_runtime.h>

// Problem constants (hardcoded in the reference)
#define NPIX 65536   // 256*256 = 2^16
#define KK   361     // 19*19
#define LSZ  19
#define HWD  256
#define QB   16      // q-rows per sub-tile
#define CT   4       // sub-tiles per chunk
#define CHUNK 64     // q per block
#define GPART (NPIX / CHUNK)      // 1024 blocks
#define NTHR 512     // 8 waves
#define NG4  ((QB * KK) / 4)      // 1444 float4 per sub-tile
#define NSLOT 8      // partial slots per row (window <= 7, one 64B line)
#define NS2  16      // s-strips for S1
#define SPS2 23      // s-rows per strip (last: 361 - 15*23 = 16)
#define DTC  82      // in2 LDS tile cols = CHUNK-1 + LSZ

// reflect-pad index (pad=9, size 256, mode="reflect"); arg is (coord + offset)
__device__ __forceinline__ int refl(int v) {
    v -= 9;
    v = v < 0 ? -v : v;
    v = v > 255 ? 510 - v : v;
    return v;
}

// ---------------------------------------------------------------------------
// S1a: partial column sums, contiguous float4 reads (the only cold HBM pass).
// ---------------------------------------------------------------------------
__global__ __launch_bounds__(256) void k_s1a(const float4* __restrict__ ker4,
                                             float4* __restrict__ part4) {
    const int p4 = blockIdx.x * 256 + threadIdx.x;   // [0, 16384)
    const int strip = blockIdx.y;
    const int s0 = strip * SPS2;
    const int n = (strip == NS2 - 1) ? (KK - s0) : SPS2;
    const float4* kp = ker4 + (size_t)s0 * (NPIX / 4) + p4;
    float4 acc = {0.f, 0.f, 0.f, 0.f};
#pragma unroll 8
    for (int s = 0; s < n; ++s) {
        float4 v = kp[(size_t)s * (NPIX / 4)];
        acc.x += v.x; acc.y += v.y; acc.z += v.z; acc.w += v.w;
    }
    part4[(size_t)strip * (NPIX / 4) + p4] = acc;
}

// S1b: rcpS1[p] = 1 / sum_strips
__global__ __launch_bounds__(256) void k_s1b(const float4* __restrict__ part4,
                                             float4* __restrict__ rcp4) {
    const int i = blockIdx.x * 256 + threadIdx.x;    // [0, 16384)
    float4 a = {0.f, 0.f, 0.f, 0.f};
#pragma unroll
    for (int s = 0; s < NS2; ++s) {
        float4 v = part4[(size_t)s * (NPIX / 4) + i];
        a.x += v.x; a.y += v.y; a.z += v.z; a.w += v.w;
    }
    rcp4[i] = float4{1.0f / a.x, 1.0f / a.y, 1.0f / a.z, 1.0f / a.w};
}

// ---------------------------------------------------------------------------
// k_part: R17 arithmetic (stagger + XCD swizzle + chunk-carry + snapshot +
// half-wave LDS rowsum) restructured as a T14 async-stage pipeline:
//   per sub-tile k: issue loads(k+1) -> named regs; accum(k) from buf[k&1]
//   (VMEM latency hides under DS+FMA); waitcnt; write buf[(k+1)&1];
//   barrier; rowsum(k+1); barrier.
// 8 barriers/block (R17: 12), stage latency fully hidden. Double-buffered
// tile: 52.8 KB LDS -> 3 blocks/CU; __launch_bounds__(512,6) holds 6
// waves/SIMD (24 waves/CU).
// ---------------------------------------------------------------------------
__global__ __launch_bounds__(NTHR, 6) void k_part(const float* __restrict__ ker,
                                                  const float* __restrict__ rcpS1,
                                                  const float* __restrict__ in2,
                                                  float2* __restrict__ partial) {
    // generation stagger (no effect on results, only phase timing)
    switch (blockIdx.x >> 8) {
        case 1: __builtin_amdgcn_s_sleep(10); break;
        case 2: __builtin_amdgcn_s_sleep(20); break;
        case 3: __builtin_amdgcn_s_sleep(30); break;
        default: break;
    }

    __shared__ float tile[2][QB * KK];   // 2 x 23,104 B
    __shared__ float dt[LSZ * DTC];      // 6,232 B
    __shared__ float rcpS2s[QB];
    const int tid = threadIdx.x;
    const int lb  = ((blockIdx.x & 7) << 7) | (blockIdx.x >> 3);  // 1024 = 8*128
    const int q0  = lb * CHUNK;
    const int wave = tid >> 6, lane = tid & 63;
    const int half = lane >> 5, l32 = lane & 31;
    const float4* rcp4 = (const float4*)rcpS1;

    // stage reflected in2 patch
    {
        const int y0 = q0 >> 8, x0 = q0 & 255;
        for (int i = tid; i < LSZ * DTC; i += NTHR) {
            int ai = i / DTC, ci = i - ai * DTC;
            dt[i] = in2[refl(y0 + ai) * HWD + refl(x0 + ci)];
        }
    }
    // prologue: direct stage(0) -> tile[0]
    {
        const int base0 = q0 * KK;
        const float4* k4 = (const float4*)(ker + base0);
#pragma unroll
        for (int j = 0; j < 3; ++j) {
            const int i = tid + j * NTHR;
            if (i < NG4) {
                float4 v = k4[i];
                const float4 s = rcp4[((base0 + i * 4) & (NPIX - 1)) >> 2];
                v.x *= s.x; v.y *= s.y; v.z *= s.z; v.w *= s.w;
                *(float4*)(&tile[0][i * 4]) = v;
            }
        }
    }
    __syncthreads();
    // rowsum(0): one row per half-wave, single round
    {
        const int row = 2 * wave + half;
        float acc = 0.f;
        for (int e = l32; e < KK; e += 32) acc += tile[0][row * KK + e];
        acc += __shfl_xor(acc, 1);  acc += __shfl_xor(acc, 2);
        acc += __shfl_xor(acc, 4);  acc += __shfl_xor(acc, 8);
        acc += __shfl_xor(acc, 16);
        if (l32 == 0) rcpS2s[row] = 1.0f / acc;
    }
    __syncthreads();

    // per-lane chunk-carry state
    const int t  = tid;
    const int j0 = t * NPIX + q0;
    const int r0 = j0 / KK;
    const int jm = j0 - r0 * KK;
    const int d0 = (jm == 0) ? CHUNK : (KK - jm);
    const int split = d0 < CHUNK ? d0 : CHUNK;     // [1, 64]
    const int la = t / LSZ, lb2 = t - LSZ * la;
    const int dbase = la * DTC + lb2;
    float ad = 0.f, as = 0.f, sd = 0.f, ss = 0.f;

#pragma unroll
    for (int k = 0; k < CT; ++k) {
        // issue loads for sub-tile k+1 into named regs (T14 split)
        float4 kv0, kv1, kv2, sv0, sv1, sv2;
        int i0 = 0, i1 = 0, i2 = 0;
        if (k < CT - 1) {
            const int basek = (q0 + (k + 1) * QB) * KK;
            const float4* k4 = (const float4*)(ker + basek);
            i0 = tid;            i1 = tid + NTHR;       i2 = tid + 2 * NTHR;
            kv0 = k4[i0];        sv0 = rcp4[((basek + i0 * 4) & (NPIX - 1)) >> 2];
            kv1 = k4[i1];        sv1 = rcp4[((basek + i1 * 4) & (NPIX - 1)) >> 2];
            if (i2 < NG4) {
                kv2 = k4[i2];    sv2 = rcp4[((basek + i2 * 4) & (NPIX - 1)) >> 2];
            }
        }
        // accum(k) from tile[k&1] (VMEM latency hides under this)
        if (t < KK) {
            const float* bc = tile[k & 1];
#pragma unroll
            for (int o = 0; o < QB; ++o) {
                const int off = k * QB + o;
                if (off == split) { sd = ad; ss = as; }  // snapshot at boundary
                float v = bc[o * KK + t] * rcpS2s[o];
                float d = dt[dbase + off];
                ad += d * v;
                as += v;
            }
        }
        if (k < CT - 1) {
            // write staged regs -> other buffer
            float* bn = tile[(k + 1) & 1];
            kv0.x *= sv0.x; kv0.y *= sv0.y; kv0.z *= sv0.z; kv0.w *= sv0.w;
            *(float4*)(&bn[i0 * 4]) = kv0;
            kv1.x *= sv1.x; kv1.y *= sv1.y; kv1.z *= sv1.z; kv1.w *= sv1.w;
            *(float4*)(&bn[i1 * 4]) = kv1;
            if (i2 < NG4) {
                kv2.x *= sv2.x; kv2.y *= sv2.y; kv2.z *= sv2.z; kv2.w *= sv2.w;
                *(float4*)(&bn[i2 * 4]) = kv2;
            }
            __syncthreads();
            // rowsum(k+1) from the freshly written buffer
            const float* bn2 = tile[(k + 1) & 1];
            const int row = 2 * wave + half;
            float acc = 0.f;
            for (int e = l32; e < KK; e += 32) acc += bn2[row * KK + e];
            acc += __shfl_xor(acc, 1);  acc += __shfl_xor(acc, 2);
            acc += __shfl_xor(acc, 4);  acc += __shfl_xor(acc, 8);
            acc += __shfl_xor(acc, 16);
            if (l32 == 0) rcpS2s[row] = 1.0f / acc;
            __syncthreads();
        }
    }

    if (t < KK) {
        const int slot = lb & (NSLOT - 1);
        if (split == CHUNK) {
            partial[(size_t)r0 * NSLOT + slot] = float2{ad, as};
        } else {
            partial[(size_t)r0 * NSLOT + slot] = float2{sd, ss};
            partial[(size_t)(r0 + 1) * NSLOT + slot] = float2{ad - sd, as - ss};
        }
    }
}

// ---------------------------------------------------------------------------
// k_out2: sum the valid slot window for row r (no zero-init needed).
// ---------------------------------------------------------------------------
__global__ __launch_bounds__(256) void k_out2(const float2* __restrict__ partial,
                                              float* __restrict__ out) {
    const int r = blockIdx.x * 256 + threadIdx.x;
    const int j0 = r * KK;
    const int qs = j0 & (NPIX - 1);
    const int ql = (j0 + KK - 1) & (NPIX - 1);
    const int first = qs >> 6;
    const int last  = ql >> 6;
    const int cnt = ((last - first) & (GPART - 1)) + 1;
    const float2* p = partial + (size_t)r * NSLOT;
    float dot = 0.f, sum = 0.f;
    for (int i = 0; i < cnt; ++i) {
        float2 v = p[(first + i) & (NSLOT - 1)];
        dot += v.x; sum += v.y;
    }
    out[r] = dot / sum;
}

// ---------------------------------------------------------------------------
// Minimal fallback path (tiny ws): direct strided gathers.
// ---------------------------------------------------------------------------
__global__ __launch_bounds__(256) void k_s1(const float* __restrict__ ker,
                                            float* __restrict__ rcpS1) {
    int p = blockIdx.x * blockDim.x + threadIdx.x;
    const float* kp = ker + p;
    float a = 0.f;
    for (int s = 0; s < KK; ++s) a += kp[(size_t)s * NPIX];
    rcpS1[p] = 1.0f / a;
}

__global__ __launch_bounds__(256) void k_s2_fallback(const float* __restrict__ ker,
                                                     const float* __restrict__ rcpS1,
                                                     float* __restrict__ rcpS2) {
    int lane = threadIdx.x & 63;
    int q = blockIdx.x * 4 + (threadIdx.x >> 6);
    int base = q * KK;
    float acc = 0.f;
    for (int t = lane; t < KK; t += 64)
        acc += ker[base + t] * rcpS1[(base + t) & (NPIX - 1)];
    for (int m = 1; m < 64; m <<= 1) acc += __shfl_xor(acc, m);
    if (lane == 0) rcpS2[q] = 1.0f / acc;
}

__global__ __launch_bounds__(256) void k_out_fallback(const float* __restrict__ ker,
                                                      const float* __restrict__ rcpS1,
                                                      const float* __restrict__ rcpS2,
                                                      const float* __restrict__ in2,
                                                      float* __restrict__ out) {
    int lane = threadIdx.x & 63;
    int r = blockIdx.x * 4 + (threadIdx.x >> 6);
    float vsum = 0.f, vdot = 0.f;
    for (int u = lane; u < KK; u += 64) {
        int jj = r * KK + u;
        int t  = jj >> 16;
        int q  = jj & (NPIX - 1);
        int m  = q * KK + t;
        float v = ker[m] * rcpS1[m & (NPIX - 1)] * rcpS2[q];
        int y = q >> 8, x = q & 255;
        int a = t / LSZ, b = t - a * LSZ;
        float d = in2[refl(y + a) * HWD + refl(x + b)];
        vsum += v;
        vdot += d * v;
    }
    for (int mm = 1; mm < 64; mm <<= 1) {
        vsum += __shfl_xor(vsum, mm);
        vdot += __shfl_xor(vdot, mm);
    }
    if (lane == 0) out[r] = vdot / vsum;
}

extern "C" void kernel_launch(void* const* d_in, const int* in_sizes, int n_in,
                              void* d_out, int out_size, void* d_ws, size_t ws_size,
                              hipStream_t stream) {
    const float* inp = (const float*)d_in[0];   // (1,3,256,256)
    const float* ker = (const float*)d_in[1];   // (19,19,256,256)
    float* out = (float*)d_out;                 // (1,1,256,256)
    const float* in2 = inp + 2 * NPIX;          // channel 2

    float*  rcpS1   = (float*)d_ws;                           // NPIX
    float*  s1part  = rcpS1 + NPIX;                           // NS2*NPIX
    float2* partial = (float2*)(s1part + (size_t)NS2 * NPIX); // NPIX*NSLOT float2

    const size_t needed = ((size_t)NPIX * (1 + NS2) +
                           (size_t)NPIX * NSLOT * 2) * sizeof(float);  // ~8.25 MB

    if (ws_size >= needed) {
        dim3 g1(NPIX / 4 / 256, NS2);   // (64, 16)
        k_s1a<<<g1, 256, 0, stream>>>((const float4*)ker, (float4*)s1part);
        k_s1b<<<NPIX / 4 / 256, 256, 0, stream>>>((const float4*)s1part, (float4*)rcpS1);
        k_part<<<GPART, NTHR, 0, stream>>>(ker, rcpS1, in2, partial);
        k_out2<<<NPIX / 256, 256, 0, stream>>>(partial, out);
    } else {
        float* rcpS2 = rcpS1 + NPIX;   // fallback needs only 512 KB
        k_s1<<<NPIX / 256, 256, 0, stream>>>(ker, rcpS1);
        k_s2_fallback<<<NPIX / 4, 256, 0, stream>>>(ker, rcpS1, rcpS2);
        k_out_fallback<<<NPIX / 4, 256, 0, stream>>>(ker, rcpS1, rcpS2, in2, out);
    }
}

// Round 19
// 47.420 us; speedup vs baseline: 1.0014x; 1.0014x over previous
//
#include <hip/hip_runtime.h>

// Problem constants (hardcoded in the reference)
#define NPIX 65536   // 256*256 = 2^16
#define KK   361     // 19*19
#define LSZ  19
#define HWD  256
#define QB   16      // q-rows per sub-tile
#define CT   4       // sub-tiles per chunk
#define CHUNK 64     // q per block
#define GPART (NPIX / CHUNK)      // 1024 blocks
#define NTHR 512     // 8 waves
#define NG4  ((QB * KK) / 4)      // 1444 float4 per sub-tile
#define NSLOT 8      // partial slots per row (window <= 7, one 64B line)
#define NS2  16      // s-strips for S1
#define SPS2 23      // s-rows per strip (last: 361 - 15*23 = 16)
#define DTC  82      // in2 LDS tile cols = CHUNK-1 + LSZ

// reflect-pad index (pad=9, size 256, mode="reflect"); arg is (coord + offset)
__device__ __forceinline__ int refl(int v) {
    v -= 9;
    v = v < 0 ? -v : v;
    v = v > 255 ? 510 - v : v;
    return v;
}

// ---------------------------------------------------------------------------
// S1a: partial column sums, contiguous float4 reads (the only cold HBM pass).
// ---------------------------------------------------------------------------
__global__ __launch_bounds__(256) void k_s1a(const float4* __restrict__ ker4,
                                             float4* __restrict__ part4) {
    const int p4 = blockIdx.x * 256 + threadIdx.x;   // [0, 16384)
    const int strip = blockIdx.y;
    const int s0 = strip * SPS2;
    const int n = (strip == NS2 - 1) ? (KK - s0) : SPS2;
    const float4* kp = ker4 + (size_t)s0 * (NPIX / 4) + p4;
    float4 acc = {0.f, 0.f, 0.f, 0.f};
#pragma unroll 8
    for (int s = 0; s < n; ++s) {
        float4 v = kp[(size_t)s * (NPIX / 4)];
        acc.x += v.x; acc.y += v.y; acc.z += v.z; acc.w += v.w;
    }
    part4[(size_t)strip * (NPIX / 4) + p4] = acc;
}

// S1b: rcpS1[p] = 1 / sum_strips
__global__ __launch_bounds__(256) void k_s1b(const float4* __restrict__ part4,
                                             float4* __restrict__ rcp4) {
    const int i = blockIdx.x * 256 + threadIdx.x;    // [0, 16384)
    float4 a = {0.f, 0.f, 0.f, 0.f};
#pragma unroll
    for (int s = 0; s < NS2; ++s) {
        float4 v = part4[(size_t)s * (NPIX / 4) + i];
        a.x += v.x; a.y += v.y; a.z += v.z; a.w += v.w;
    }
    rcp4[i] = float4{1.0f / a.x, 1.0f / a.y, 1.0f / a.z, 1.0f / a.w};
}

// ---------------------------------------------------------------------------
// k_part: R17 arithmetic (stagger + XCD swizzle + chunk-carry + snapshot +
// half-wave LDS rowsum) restructured as a T14 async-stage pipeline:
//   per sub-tile k: issue loads(k+1) -> named regs; accum(k) from buf[k&1]
//   (VMEM latency hides under DS+FMA); waitcnt; write buf[(k+1)&1];
//   barrier; rowsum(k+1); barrier.
// 8 barriers/block (R17: 12), stage latency fully hidden. Double-buffered
// tile: 52.8 KB LDS -> 3 blocks/CU; __launch_bounds__(512,6) holds 6
// waves/SIMD (24 waves/CU).
// ---------------------------------------------------------------------------
__global__ __launch_bounds__(NTHR, 6) void k_part(const float* __restrict__ ker,
                                                  const float* __restrict__ rcpS1,
                                                  const float* __restrict__ in2,
                                                  float2* __restrict__ partial) {
    // generation stagger (no effect on results, only phase timing)
    switch (blockIdx.x >> 8) {
        case 1: __builtin_amdgcn_s_sleep(10); break;
        case 2: __builtin_amdgcn_s_sleep(20); break;
        case 3: __builtin_amdgcn_s_sleep(30); break;
        default: break;
    }

    __shared__ float tile[2][QB * KK];   // 2 x 23,104 B
    __shared__ float dt[LSZ * DTC];      // 6,232 B
    __shared__ float rcpS2s[QB];
    const int tid = threadIdx.x;
    const int lb  = ((blockIdx.x & 7) << 7) | (blockIdx.x >> 3);  // 1024 = 8*128
    const int q0  = lb * CHUNK;
    const int wave = tid >> 6, lane = tid & 63;
    const int half = lane >> 5, l32 = lane & 31;
    const float4* rcp4 = (const float4*)rcpS1;

    // stage reflected in2 patch
    {
        const int y0 = q0 >> 8, x0 = q0 & 255;
        for (int i = tid; i < LSZ * DTC; i += NTHR) {
            int ai = i / DTC, ci = i - ai * DTC;
            dt[i] = in2[refl(y0 + ai) * HWD + refl(x0 + ci)];
        }
    }
    // prologue: direct stage(0) -> tile[0]
    {
        const int base0 = q0 * KK;
        const float4* k4 = (const float4*)(ker + base0);
#pragma unroll
        for (int j = 0; j < 3; ++j) {
            const int i = tid + j * NTHR;
            if (i < NG4) {
                float4 v = k4[i];
                const float4 s = rcp4[((base0 + i * 4) & (NPIX - 1)) >> 2];
                v.x *= s.x; v.y *= s.y; v.z *= s.z; v.w *= s.w;
                *(float4*)(&tile[0][i * 4]) = v;
            }
        }
    }
    __syncthreads();
    // rowsum(0): one row per half-wave, single round
    {
        const int row = 2 * wave + half;
        float acc = 0.f;
        for (int e = l32; e < KK; e += 32) acc += tile[0][row * KK + e];
        acc += __shfl_xor(acc, 1);  acc += __shfl_xor(acc, 2);
        acc += __shfl_xor(acc, 4);  acc += __shfl_xor(acc, 8);
        acc += __shfl_xor(acc, 16);
        if (l32 == 0) rcpS2s[row] = 1.0f / acc;
    }
    __syncthreads();

    // per-lane chunk-carry state
    const int t  = tid;
    const int j0 = t * NPIX + q0;
    const int r0 = j0 / KK;
    const int jm = j0 - r0 * KK;
    const int d0 = (jm == 0) ? CHUNK : (KK - jm);
    const int split = d0 < CHUNK ? d0 : CHUNK;     // [1, 64]
    const int la = t / LSZ, lb2 = t - LSZ * la;
    const int dbase = la * DTC + lb2;
    float ad = 0.f, as = 0.f, sd = 0.f, ss = 0.f;

#pragma unroll
    for (int k = 0; k < CT; ++k) {
        // issue loads for sub-tile k+1 into named regs (T14 split)
        float4 kv0, kv1, kv2, sv0, sv1, sv2;
        int i0 = 0, i1 = 0, i2 = 0;
        if (k < CT - 1) {
            const int basek = (q0 + (k + 1) * QB) * KK;
            const float4* k4 = (const float4*)(ker + basek);
            i0 = tid;            i1 = tid + NTHR;       i2 = tid + 2 * NTHR;
            kv0 = k4[i0];        sv0 = rcp4[((basek + i0 * 4) & (NPIX - 1)) >> 2];
            kv1 = k4[i1];        sv1 = rcp4[((basek + i1 * 4) & (NPIX - 1)) >> 2];
            if (i2 < NG4) {
                kv2 = k4[i2];    sv2 = rcp4[((basek + i2 * 4) & (NPIX - 1)) >> 2];
            }
        }
        // accum(k) from tile[k&1] (VMEM latency hides under this)
        if (t < KK) {
            const float* bc = tile[k & 1];
#pragma unroll
            for (int o = 0; o < QB; ++o) {
                const int off = k * QB + o;
                if (off == split) { sd = ad; ss = as; }  // snapshot at boundary
                float v = bc[o * KK + t] * rcpS2s[o];
                float d = dt[dbase + off];
                ad += d * v;
                as += v;
            }
        }
        if (k < CT - 1) {
            // write staged regs -> other buffer
            float* bn = tile[(k + 1) & 1];
            kv0.x *= sv0.x; kv0.y *= sv0.y; kv0.z *= sv0.z; kv0.w *= sv0.w;
            *(float4*)(&bn[i0 * 4]) = kv0;
            kv1.x *= sv1.x; kv1.y *= sv1.y; kv1.z *= sv1.z; kv1.w *= sv1.w;
            *(float4*)(&bn[i1 * 4]) = kv1;
            if (i2 < NG4) {
                kv2.x *= sv2.x; kv2.y *= sv2.y; kv2.z *= sv2.z; kv2.w *= sv2.w;
                *(float4*)(&bn[i2 * 4]) = kv2;
            }
            __syncthreads();
            // rowsum(k+1) from the freshly written buffer
            const float* bn2 = tile[(k + 1) & 1];
            const int row = 2 * wave + half;
            float acc = 0.f;
            for (int e = l32; e < KK; e += 32) acc += bn2[row * KK + e];
            acc += __shfl_xor(acc, 1);  acc += __shfl_xor(acc, 2);
            acc += __shfl_xor(acc, 4);  acc += __shfl_xor(acc, 8);
            acc += __shfl_xor(acc, 16);
            if (l32 == 0) rcpS2s[row] = 1.0f / acc;
            __syncthreads();
        }
    }

    if (t < KK) {
        const int slot = lb & (NSLOT - 1);
        if (split == CHUNK) {
            partial[(size_t)r0 * NSLOT + slot] = float2{ad, as};
        } else {
            partial[(size_t)r0 * NSLOT + slot] = float2{sd, ss};
            partial[(size_t)(r0 + 1) * NSLOT + slot] = float2{ad - sd, as - ss};
        }
    }
}

// ---------------------------------------------------------------------------
// k_out2: sum the valid slot window for row r (no zero-init needed).
// ---------------------------------------------------------------------------
__global__ __launch_bounds__(256) void k_out2(const float2* __restrict__ partial,
                                              float* __restrict__ out) {
    const int r = blockIdx.x * 256 + threadIdx.x;
    const int j0 = r * KK;
    const int qs = j0 & (NPIX - 1);
    const int ql = (j0 + KK - 1) & (NPIX - 1);
    const int first = qs >> 6;
    const int last  = ql >> 6;
    const int cnt = ((last - first) & (GPART - 1)) + 1;
    const float2* p = partial + (size_t)r * NSLOT;
    float dot = 0.f, sum = 0.f;
    for (int i = 0; i < cnt; ++i) {
        float2 v = p[(first + i) & (NSLOT - 1)];
        dot += v.x; sum += v.y;
    }
    out[r] = dot / sum;
}

// ---------------------------------------------------------------------------
// Minimal fallback path (tiny ws): direct strided gathers.
// ---------------------------------------------------------------------------
__global__ __launch_bounds__(256) void k_s1(const float* __restrict__ ker,
                                            float* __restrict__ rcpS1) {
    int p = blockIdx.x * blockDim.x + threadIdx.x;
    const float* kp = ker + p;
    float a = 0.f;
    for (int s = 0; s < KK; ++s) a += kp[(size_t)s * NPIX];
    rcpS1[p] = 1.0f / a;
}

__global__ __launch_bounds__(256) void k_s2_fallback(const float* __restrict__ ker,
                                                     const float* __restrict__ rcpS1,
                                                     float* __restrict__ rcpS2) {
    int lane = threadIdx.x & 63;
    int q = blockIdx.x * 4 + (threadIdx.x >> 6);
    int base = q * KK;
    float acc = 0.f;
    for (int t = lane; t < KK; t += 64)
        acc += ker[base + t] * rcpS1[(base + t) & (NPIX - 1)];
    for (int m = 1; m < 64; m <<= 1) acc += __shfl_xor(acc, m);
    if (lane == 0) rcpS2[q] = 1.0f / acc;
}

__global__ __launch_bounds__(256) void k_out_fallback(const float* __restrict__ ker,
                                                      const float* __restrict__ rcpS1,
                                                      const float* __restrict__ rcpS2,
                                                      const float* __restrict__ in2,
                                                      float* __restrict__ out) {
    int lane = threadIdx.x & 63;
    int r = blockIdx.x * 4 + (threadIdx.x >> 6);
    float vsum = 0.f, vdot = 0.f;
    for (int u = lane; u < KK; u += 64) {
        int jj = r * KK + u;
        int t  = jj >> 16;
        int q  = jj & (NPIX - 1);
        int m  = q * KK + t;
        float v = ker[m] * rcpS1[m & (NPIX - 1)] * rcpS2[q];
        int y = q >> 8, x = q & 255;
        int a = t / LSZ, b = t - a * LSZ;
        float d = in2[refl(y + a) * HWD + refl(x + b)];
        vsum += v;
        vdot += d * v;
    }
    for (int mm = 1; mm < 64; mm <<= 1) {
        vsum += __shfl_xor(vsum, mm);
        vdot += __shfl_xor(vdot, mm);
    }
    if (lane == 0) out[r] = vdot / vsum;
}

extern "C" void kernel_launch(void* const* d_in, const int* in_sizes, int n_in,
                              void* d_out, int out_size, void* d_ws, size_t ws_size,
                              hipStream_t stream) {
    const float* inp = (const float*)d_in[0];   // (1,3,256,256)
    const float* ker = (const float*)d_in[1];   // (19,19,256,256)
    float* out = (float*)d_out;                 // (1,1,256,256)
    const float* in2 = inp + 2 * NPIX;          // channel 2

    float*  rcpS1   = (float*)d_ws;                           // NPIX
    float*  s1part  = rcpS1 + NPIX;                           // NS2*NPIX
    float2* partial = (float2*)(s1part + (size_t)NS2 * NPIX); // NPIX*NSLOT float2

    const size_t needed = ((size_t)NPIX * (1 + NS2) +
                           (size_t)NPIX * NSLOT * 2) * sizeof(float);  // ~8.25 MB

    if (ws_size >= needed) {
        dim3 g1(NPIX / 4 / 256, NS2);   // (64, 16)
        k_s1a<<<g1, 256, 0, stream>>>((const float4*)ker, (float4*)s1part);
        k_s1b<<<NPIX / 4 / 256, 256, 0, stream>>>((const float4*)s1part, (float4*)rcpS1);
        k_part<<<GPART, NTHR, 0, stream>>>(ker, rcpS1, in2, partial);
        k_out2<<<NPIX / 256, 256, 0, stream>>>(partial, out);
    } else {
        float* rcpS2 = rcpS1 + NPIX;   // fallback needs only 512 KB
        k_s1<<<NPIX / 256, 256, 0, stream>>>(ker, rcpS1);
        k_s2_fallback<<<NPIX / 4, 256, 0, stream>>>(ker, rcpS1, rcpS2);
        k_out_fallback<<<NPIX / 4, 256, 0, stream>>>(ker, rcpS1, rcpS2, in2, out);
    }
}

// Round 20
// 45.531 us; speedup vs baseline: 1.0430x; 1.0415x over previous
//
#include <hip/hip_runtime.h>

// Problem constants (hardcoded in the reference)
#define NPIX 65536   // 256*256 = 2^16
#define KK   361     // 19*19
#define LSZ  19
#define HWD  256
#define QB   16      // q-rows per sub-tile
#define CT   4       // sub-tiles per chunk
#define CHUNK 64     // q per block
#define GPART (NPIX / CHUNK)      // 1024 blocks
#define NTHR 512     // 8 waves: full 32-wave/CU occupancy at 4 blocks/CU
#define NSLOT 8      // partial slots per row (window <= 7, one 64B line)
#define NS2  16      // s-strips for S1
#define SPS2 23      // s-rows per strip (last: 361 - 15*23 = 16)
#define DTC  82      // in2 LDS tile cols = CHUNK-1 + LSZ

// reflect-pad index (pad=9, size 256, mode="reflect"); arg is (coord + offset)
__device__ __forceinline__ int refl(int v) {
    v -= 9;
    v = v < 0 ? -v : v;
    v = v > 255 ? 510 - v : v;
    return v;
}

// ---------------------------------------------------------------------------
// S1a: partial column sums, contiguous float4 reads (the only cold HBM pass).
// ---------------------------------------------------------------------------
__global__ __launch_bounds__(256) void k_s1a(const float4* __restrict__ ker4,
                                             float4* __restrict__ part4) {
    const int p4 = blockIdx.x * 256 + threadIdx.x;   // [0, 16384)
    const int strip = blockIdx.y;
    const int s0 = strip * SPS2;
    const int n = (strip == NS2 - 1) ? (KK - s0) : SPS2;
    const float4* kp = ker4 + (size_t)s0 * (NPIX / 4) + p4;
    float4 acc = {0.f, 0.f, 0.f, 0.f};
#pragma unroll 8
    for (int s = 0; s < n; ++s) {
        float4 v = kp[(size_t)s * (NPIX / 4)];
        acc.x += v.x; acc.y += v.y; acc.z += v.z; acc.w += v.w;
    }
    part4[(size_t)strip * (NPIX / 4) + p4] = acc;
}

// S1b: rcpS1[p] = 1 / sum_strips
__global__ __launch_bounds__(256) void k_s1b(const float4* __restrict__ part4,
                                             float4* __restrict__ rcp4) {
    const int i = blockIdx.x * 256 + threadIdx.x;    // [0, 16384)
    float4 a = {0.f, 0.f, 0.f, 0.f};
#pragma unroll
    for (int s = 0; s < NS2; ++s) {
        float4 v = part4[(size_t)s * (NPIX / 4) + i];
        a.x += v.x; a.y += v.y; a.z += v.z; a.w += v.w;
    }
    rcp4[i] = float4{1.0f / a.x, 1.0f / a.y, 1.0f / a.z, 1.0f / a.w};
}

// ---------------------------------------------------------------------------
// k_part (CHAMPION, R17): stagger + XCD swizzle + chunk-carry + snapshot +
// half-wave LDS rowsum + full occupancy.
//   - NTHR=512 (8 waves): 4 blocks/CU x 8 = 32 waves/CU (full).
//   - rowsum: ONE row per HALF-wave (8 waves x 2 halves = 16 rows in a
//     single round): 12 stride-32 LDS reads (2-way bank alias = free) +
//     5 intra-32 shuffles. Rowsum stays in LDS: 5 variants that moved it
//     (R10/R11/R13/R15/R16) all lost — it is latency-bound.
//   - T14 dbuf pipeline (R19) lost: occupancy 32->24 cost > barrier savings.
// ---------------------------------------------------------------------------
__global__ __launch_bounds__(NTHR) void k_part(const float* __restrict__ ker,
                                               const float* __restrict__ rcpS1,
                                               const float* __restrict__ in2,
                                               float2* __restrict__ partial) {
    // generation stagger (no effect on results, only phase timing):
    // de-phases the 4 same-CU dispatch generations so stage VMEM overlaps
    // neighbors' accum DS (convoy-breaking, R14: -2.3 us).
    switch (blockIdx.x >> 8) {
        case 1: __builtin_amdgcn_s_sleep(10); break;
        case 2: __builtin_amdgcn_s_sleep(20); break;
        case 3: __builtin_amdgcn_s_sleep(30); break;
        default: break;
    }

    __shared__ float tile[QB * KK];      // 23,104 B
    __shared__ float dt[LSZ * DTC];      // 6,232 B
    __shared__ float rcpS2s[QB];
    const int tid = threadIdx.x;
    const int lb  = ((blockIdx.x & 7) << 7) | (blockIdx.x >> 3);  // 1024 = 8*128
    const int q0  = lb * CHUNK;

    // stage reflected in2 patch (consumed after the k=0 stage barrier)
    {
        const int y0 = q0 >> 8, x0 = q0 & 255;
        for (int i = tid; i < LSZ * DTC; i += NTHR) {
            int ai = i / DTC, ci = i - ai * DTC;
            dt[i] = in2[refl(y0 + ai) * HWD + refl(x0 + ci)];
        }
    }

    // per-lane chunk-carry state
    const int t  = tid;
    const int j0 = t * NPIX + q0;             // < 2^25 for t<512
    const int r0 = j0 / KK;
    const int jm = j0 - r0 * KK;
    const int d0 = (jm == 0) ? CHUNK : (KK - jm);
    const int split = d0 < CHUNK ? d0 : CHUNK;     // [1, 64]
    const int la = t / LSZ, lb2 = t - LSZ * la;
    const int dbase = la * DTC + lb2;
    float ad = 0.f, as = 0.f, sd = 0.f, ss = 0.f;
    const int wave = tid >> 6, lane = tid & 63;
    const int half = lane >> 5, l32 = lane & 31;

    for (int k = 0; k < CT; ++k) {
        __syncthreads();   // previous sub-tile fully consumed (and dt, k=0)
        // stage ker sub-tile k (coalesced float4), scaled by rcpS1
        const int basek = (q0 + k * QB) * KK;            // %4 == 0
        const float4* k4 = (const float4*)(ker + basek);
        for (int i = tid; i < (QB * KK) / 4; i += NTHR) {
            float4 v = k4[i];
            int m = basek + i * 4;
            const float4 s = *(const float4*)(rcpS1 + (m & (NPIX - 1)));
            v.x *= s.x; v.y *= s.y; v.z *= s.z; v.w *= s.w;
            *(float4*)(tile + i * 4) = v;
        }
        __syncthreads();
        // per-q row sums -> rcpS2s: one row per half-wave, single round.
        {
            const int row = 2 * wave + half;             // 0..15, all threads
            float acc = 0.f;
            for (int e = l32; e < KK; e += 32) acc += tile[row * KK + e];
            acc += __shfl_xor(acc, 1);
            acc += __shfl_xor(acc, 2);
            acc += __shfl_xor(acc, 4);
            acc += __shfl_xor(acc, 8);
            acc += __shfl_xor(acc, 16);
            if (l32 == 0) rcpS2s[row] = 1.0f / acc;
        }
        __syncthreads();
        if (t < KK) {
#pragma unroll
            for (int o = 0; o < QB; ++o) {
                const int off = k * QB + o;
                if (off == split) { sd = ad; ss = as; }  // snapshot at boundary
                float v = tile[o * KK + t] * rcpS2s[o];
                float d = dt[dbase + off];
                ad += d * v;
                as += v;
            }
        }
    }

    if (t < KK) {
        const int slot = lb & (NSLOT - 1);
        if (split == CHUNK) {
            partial[(size_t)r0 * NSLOT + slot] = float2{ad, as};
        } else {
            partial[(size_t)r0 * NSLOT + slot] = float2{sd, ss};
            partial[(size_t)(r0 + 1) * NSLOT + slot] = float2{ad - sd, as - ss};
        }
    }
}

// ---------------------------------------------------------------------------
// k_out2: sum the valid slot window for row r (no zero-init needed).
// Chunks touching row r: [qs>>6 .. ql>>6] (mod GPART), <= 7 wide;
// slots = chunk & 7, distinct. Whole window lives in ONE 64B line.
// ---------------------------------------------------------------------------
__global__ __launch_bounds__(256) void k_out2(const float2* __restrict__ partial,
                                              float* __restrict__ out) {
    const int r = blockIdx.x * 256 + threadIdx.x;
    const int j0 = r * KK;
    const int qs = j0 & (NPIX - 1);
    const int ql = (j0 + KK - 1) & (NPIX - 1);
    const int first = qs >> 6;
    const int last  = ql >> 6;
    const int cnt = ((last - first) & (GPART - 1)) + 1;
    const float2* p = partial + (size_t)r * NSLOT;
    float dot = 0.f, sum = 0.f;
    for (int i = 0; i < cnt; ++i) {
        float2 v = p[(first + i) & (NSLOT - 1)];
        dot += v.x; sum += v.y;
    }
    out[r] = dot / sum;
}

// ---------------------------------------------------------------------------
// Minimal fallback path (tiny ws): direct strided gathers.
// ---------------------------------------------------------------------------
__global__ __launch_bounds__(256) void k_s1(const float* __restrict__ ker,
                                            float* __restrict__ rcpS1) {
    int p = blockIdx.x * blockDim.x + threadIdx.x;
    const float* kp = ker + p;
    float a = 0.f;
    for (int s = 0; s < KK; ++s) a += kp[(size_t)s * NPIX];
    rcpS1[p] = 1.0f / a;
}

__global__ __launch_bounds__(256) void k_s2_fallback(const float* __restrict__ ker,
                                                     const float* __restrict__ rcpS1,
                                                     float* __restrict__ rcpS2) {
    int lane = threadIdx.x & 63;
    int q = blockIdx.x * 4 + (threadIdx.x >> 6);
    int base = q * KK;
    float acc = 0.f;
    for (int t = lane; t < KK; t += 64)
        acc += ker[base + t] * rcpS1[(base + t) & (NPIX - 1)];
    for (int m = 1; m < 64; m <<= 1) acc += __shfl_xor(acc, m);
    if (lane == 0) rcpS2[q] = 1.0f / acc;
}

__global__ __launch_bounds__(256) void k_out_fallback(const float* __restrict__ ker,
                                                      const float* __restrict__ rcpS1,
                                                      const float* __restrict__ rcpS2,
                                                      const float* __restrict__ in2,
                                                      float* __restrict__ out) {
    int lane = threadIdx.x & 63;
    int r = blockIdx.x * 4 + (threadIdx.x >> 6);
    float vsum = 0.f, vdot = 0.f;
    for (int u = lane; u < KK; u += 64) {
        int jj = r * KK + u;
        int t  = jj >> 16;
        int q  = jj & (NPIX - 1);
        int m  = q * KK + t;
        float v = ker[m] * rcpS1[m & (NPIX - 1)] * rcpS2[q];
        int y = q >> 8, x = q & 255;
        int a = t / LSZ, b = t - a * LSZ;
        float d = in2[refl(y + a) * HWD + refl(x + b)];
        vsum += v;
        vdot += d * v;
    }
    for (int mm = 1; mm < 64; mm <<= 1) {
        vsum += __shfl_xor(vsum, mm);
        vdot += __shfl_xor(vdot, mm);
    }
    if (lane == 0) out[r] = vdot / vsum;
}

extern "C" void kernel_launch(void* const* d_in, const int* in_sizes, int n_in,
                              void* d_out, int out_size, void* d_ws, size_t ws_size,
                              hipStream_t stream) {
    const float* inp = (const float*)d_in[0];   // (1,3,256,256)
    const float* ker = (const float*)d_in[1];   // (19,19,256,256)
    float* out = (float*)d_out;                 // (1,1,256,256)
    const float* in2 = inp + 2 * NPIX;          // channel 2

    float*  rcpS1   = (float*)d_ws;                           // NPIX
    float*  s1part  = rcpS1 + NPIX;                           // NS2*NPIX
    float2* partial = (float2*)(s1part + (size_t)NS2 * NPIX); // NPIX*NSLOT float2

    const size_t needed = ((size_t)NPIX * (1 + NS2) +
                           (size_t)NPIX * NSLOT * 2) * sizeof(float);  // ~8.25 MB

    if (ws_size >= needed) {
        dim3 g1(NPIX / 4 / 256, NS2);   // (64, 16)
        k_s1a<<<g1, 256, 0, stream>>>((const float4*)ker, (float4*)s1part);
        k_s1b<<<NPIX / 4 / 256, 256, 0, stream>>>((const float4*)s1part, (float4*)rcpS1);
        k_part<<<GPART, NTHR, 0, stream>>>(ker, rcpS1, in2, partial);
        k_out2<<<NPIX / 256, 256, 0, stream>>>(partial, out);
    } else {
        float* rcpS2 = rcpS1 + NPIX;   // fallback needs only 512 KB
        k_s1<<<NPIX / 256, 256, 0, stream>>>(ker, rcpS1);
        k_s2_fallback<<<NPIX / 4, 256, 0, stream>>>(ker, rcpS1, rcpS2);
        k_out_fallback<<<NPIX / 4, 256, 0, stream>>>(ker, rcpS1, rcpS2, in2, out);
    }
}